// Round 9
// baseline (161.834 us; speedup 1.0000x reference)
//
#include <hip/hip_runtime.h>

typedef short short8 __attribute__((ext_vector_type(8)));
typedef float f32x4 __attribute__((ext_vector_type(4)));
typedef float f32x4v __attribute__((ext_vector_type(4)));

#define NROWS 65536        // B*T = 32*2048
#define NCOMPACT 640       // compacted+padded OUT columns

__device__ __forceinline__ short f2bf(float f) {
  union { float f; unsigned u; } c; c.f = f;
  unsigned r = (c.u + 0x7fffu + ((c.u >> 16) & 1u)) >> 16;
  return (short)r;
}

__device__ __forceinline__ float fastrcp(float a) {
  float r; asm("v_rcp_f32 %0, %1" : "=v"(r) : "v"(a)); return r;
}

// Map compacted column n -> original W3/b3 column (or -1 for zero pad).
// [0,32): logscales[32+j]  [32,64): biases[32+j]  [64,72): logits[k]
// [96,352): mu[k][32+j]  [352,608): logstd[k][32+j]
__device__ __forceinline__ int w3col(int n) {
  if (n < 32)  return 32 + n;
  if (n < 64)  return 96 + (n - 32);
  if (n < 72)  return 128 + (n - 64);
  if (n < 96)  return -1;
  if (n < 352) { int q = n - 96;  return 168 + (q >> 5) * 64 + (q & 31); }
  if (n < 608) { int q = n - 352; return 680 + (q >> 5) * 64 + (q & 31); }
  return -1;
}

// Build transposed bf16 weights: w1t[512][32], w2t[512][512], w3t[640][512], b3c[640]
__global__ __launch_bounds__(256) void prep_w_kernel(
    const float* __restrict__ W1, const float* __restrict__ W2,
    const float* __restrict__ W3, const float* __restrict__ b3,
    short* __restrict__ w1t, short* __restrict__ w2t,
    short* __restrict__ w3t, float* __restrict__ b3c) {
  const int NW1 = 512 * 32, NW2 = 512 * 512, NW3 = NCOMPACT * 512;
  int t = blockIdx.x * 256 + threadIdx.x;
  if (t < NW1) {
    int n = t >> 5, k = t & 31;
    w1t[t] = f2bf(W1[k * 512 + n]);
  } else if (t < NW1 + NW2) {
    int i = t - NW1; int n = i >> 9, k = i & 511;
    w2t[i] = f2bf(W2[k * 512 + n]);
  } else if (t < NW1 + NW2 + NW3) {
    int i = t - NW1 - NW2; int n = i >> 9, k = i & 511;
    int c = w3col(n);
    w3t[i] = (c >= 0) ? f2bf(W3[(size_t)k * 1160 + c]) : (short)0;
  } else if (t < NW1 + NW2 + NW3 + NCOMPACT) {
    int n = t - NW1 - NW2 - NW3;
    int c = w3col(n);
    b3c[n] = (c >= 0) ? b3[c] : 0.0f;
  }
}

// ============================ MEGAKERNEL ============================
// Block = 64 rows, 16 waves (2Mx8N: wr=wid>>3 row-group of 32, wc=wid&7 col-group).
// h1/h2 never leave LDS; weights streamed from L2 (1.2 MB total, L2-resident).
// LDS map:
//   A: [0, 4096)        xc [64][32] bf16, chunk swz (row>>1)&3
//   B: [4096, 45056)    W-stream buf0 (40 KB)
//   C: [45056, 86016)   W-stream buf1 (40 KB)
//   H: [86016, 151552)  h [64][512] bf16, elem swz ^((row&7)<<3)  (2-way = free)
//   transform plds [32][644] f32 = 82432 B over [0,82432) (A,B,C dead by then)
#define OFF_A 0
#define OFF_B 4096
#define OFF_C 45056
#define OFF_H 86016
#define PSTR 644

__global__ __launch_bounds__(1024) void mega_kernel(
    const float* __restrict__ x,      // fp32 [NROWS][64]
    const short* __restrict__ w1t,    // bf16 [512][32]
    const float* __restrict__ b1,     // fp32 [512]
    const short* __restrict__ w2t,    // bf16 [512][512]
    const float* __restrict__ b2,     // fp32 [512]
    const short* __restrict__ w3t,    // bf16 [640][512]
    const float* __restrict__ b3c,    // fp32 [640]
    float* __restrict__ out) {
  __shared__ __attribute__((aligned(16))) char lds[151552];
  const int tid = threadIdx.x;
  const int m0 = blockIdx.x * 64;
  const int lane = tid & 63, wid = tid >> 6;   // wid 0..15
  const int wr = wid >> 3, wc = wid & 7;       // wr: 32-row group, wc: col group
  const int lr = lane & 15, hi = lane >> 4, lk = hi * 8;
  short* Hs = (short*)(lds + OFF_H);

  // Stage nchunk 16B-chunks of a [rows][32] bf16 K-slice (src row stride = stride
  // elems) into LDS at bo, source-side XOR swizzle g(row)=(row>>1)&3.
  auto STAGE_W = [&](int bo, const short* src, int stride, int kt, int nchunk) {
    for (int base = wid * 64; base < nchunk; base += 1024) {
      int c = base + lane;
      int row = c >> 2;
      int skb = ((c & 3) ^ ((row >> 1) & 3)) << 4;
      const char* g = (const char*)(src + (size_t)row * stride + kt) + skb;
      __builtin_amdgcn_global_load_lds(
          (const __attribute__((address_space(1))) void*)g,
          (__attribute__((address_space(3))) void*)(lds + bo + (size_t)base * 16),
          16, 0, 0);
    }
  };

  // ---- Phase 0: stage xc (x[:, :32] -> bf16, ds_write) + w1t (gload_lds) ----
  if (tid < 256) {
    int row = tid >> 2, seg = tid & 3;
    const float* src = x + (size_t)(m0 + row) * 64 + seg * 8;
    f32x4 v0 = *(const f32x4*)src;
    f32x4 v1 = *(const f32x4*)(src + 4);
    short8 v;
#pragma unroll
    for (int i = 0; i < 4; ++i) { v[i] = f2bf(v0[i]); v[4 + i] = f2bf(v1[i]); }
    int sseg = seg ^ ((row >> 1) & 3);
    *(short8*)(lds + OFF_A + row * 64 + sseg * 16) = v;
  }
  STAGE_W(OFF_B, w1t, 32, 0, 2048);
  __syncthreads();

  // ---- Phase 1: h1 = relu(xc @ W1^T + b1) -> H (wave = 32 rows x 64 cols) ----
  {
    const short* As = (const short*)(lds + OFF_A);
    const short* Ws = (const short*)(lds + OFF_B);
    f32x4 acc1[2][4] = {};
    short8 af[2];
#pragma unroll
    for (int mi = 0; mi < 2; ++mi) {
      int row = wr * 32 + mi * 16 + lr;
      af[mi] = *(const short8*)(&As[row * 32 + (lk ^ (((row >> 1) & 3) << 3))]);
    }
#pragma unroll
    for (int ni = 0; ni < 4; ++ni) {
      int brow = wc * 64 + ni * 16 + lr;
      short8 bf_ = *(const short8*)(&Ws[brow * 32 + (lk ^ (((brow >> 1) & 3) << 3))]);
      acc1[0][ni] = __builtin_amdgcn_mfma_f32_16x16x32_bf16(af[0], bf_, acc1[0][ni], 0, 0, 0);
      acc1[1][ni] = __builtin_amdgcn_mfma_f32_16x16x32_bf16(af[1], bf_, acc1[1][ni], 0, 0, 0);
    }
    // write h1 (relu+bias) into H with elem swz
#pragma unroll
    for (int ni = 0; ni < 4; ++ni) {
      int col = wc * 64 + ni * 16 + lr;
      float bv = b1[col];
#pragma unroll
      for (int mi = 0; mi < 2; ++mi) {
#pragma unroll
        for (int j = 0; j < 4; ++j) {
          int row = wr * 32 + mi * 16 + hi * 4 + j;
          float v = fmaxf(acc1[mi][j >= 0 ? ni : ni][j] + bv, 0.0f);
          Hs[row * 512 + (col ^ ((row & 7) << 3))] = f2bf(v);
        }
      }
    }
  }
  STAGE_W(OFF_C, w2t, 512, 0, 2048);      // W2 chunk 0 (C unread so far)
  __syncthreads();                         // h1 visible + chunk0 landed

  // ---- Phase 2: h2 = relu(h1 @ W2^T + b2); BK=32 x 16 steps, dbuf C/B ----
  {
    f32x4 acc2[2][4] = {};
    for (int t = 0; t < 16; ++t) {
      int buf  = (t & 1) ? OFF_B : OFF_C;
      if (t < 15) STAGE_W((t & 1) ? OFF_C : OFF_B, w2t, 512, (t + 1) * 32, 2048);
      const short* Ws = (const short*)(lds + buf);
      short8 af[2];
#pragma unroll
      for (int mi = 0; mi < 2; ++mi) {
        int row = wr * 32 + mi * 16 + lr;
        af[mi] = *(const short8*)(&Hs[row * 512 + ((t * 32 + lk) ^ ((row & 7) << 3))]);
      }
      __builtin_amdgcn_s_setprio(1);
#pragma unroll
      for (int ni = 0; ni < 4; ++ni) {
        int brow = wc * 64 + ni * 16 + lr;
        short8 bf_ = *(const short8*)(&Ws[brow * 32 + (lk ^ (((brow >> 1) & 3) << 3))]);
        acc2[0][ni] = __builtin_amdgcn_mfma_f32_16x16x32_bf16(af[0], bf_, acc2[0][ni], 0, 0, 0);
        acc2[1][ni] = __builtin_amdgcn_mfma_f32_16x16x32_bf16(af[1], bf_, acc2[1][ni], 0, 0, 0);
      }
      __builtin_amdgcn_s_setprio(0);
      __syncthreads();
    }
    // write h2 over H (all h1 reads completed at final sync)
#pragma unroll
    for (int ni = 0; ni < 4; ++ni) {
      int col = wc * 64 + ni * 16 + lr;
      float bv = b2[col];
#pragma unroll
      for (int mi = 0; mi < 2; ++mi) {
#pragma unroll
        for (int j = 0; j < 4; ++j) {
          int row = wr * 32 + mi * 16 + hi * 4 + j;
          float v = fmaxf(acc2[mi][ni][j] + bv, 0.0f);
          Hs[row * 512 + (col ^ ((row & 7) << 3))] = f2bf(v);
        }
      }
    }
  }
  STAGE_W(OFF_C, w3t, 512, 0, 2560);      // W3 chunk 0 (C last read at t=14, safe)
  __syncthreads();                         // h2 visible + chunk0 landed

  // ---- Phase 3: params acc = h2 @ W3^T; wave = 32 rows x 80 cols ----
  f32x4 acc3[2][5] = {};
  for (int t = 0; t < 16; ++t) {
    int buf = (t & 1) ? OFF_B : OFF_C;
    if (t < 15) STAGE_W((t & 1) ? OFF_C : OFF_B, w3t, 512, (t + 1) * 32, 2560);
    const short* Ws = (const short*)(lds + buf);
    short8 af[2];
#pragma unroll
    for (int mi = 0; mi < 2; ++mi) {
      int row = wr * 32 + mi * 16 + lr;
      af[mi] = *(const short8*)(&Hs[row * 512 + ((t * 32 + lk) ^ ((row & 7) << 3))]);
    }
    __builtin_amdgcn_s_setprio(1);
#pragma unroll
    for (int ni = 0; ni < 5; ++ni) {
      int brow = wc * 80 + ni * 16 + lr;
      short8 bf_ = *(const short8*)(&Ws[brow * 32 + (lk ^ (((brow >> 1) & 3) << 3))]);
      acc3[0][ni] = __builtin_amdgcn_mfma_f32_16x16x32_bf16(af[0], bf_, acc3[0][ni], 0, 0, 0);
      acc3[1][ni] = __builtin_amdgcn_mfma_f32_16x16x32_bf16(af[1], bf_, acc3[1][ni], 0, 0, 0);
    }
    __builtin_amdgcn_s_setprio(0);
    __syncthreads();
  }

  // ---- Phase 4: transform epilogue, two 32-row phases through plds ----
  float* plds = (float*)lds;               // [32][PSTR] f32, over dead A/B/C
  float* xo  = out;
  float* ldo = out + (size_t)NROWS * 64;
#pragma unroll
  for (int p = 0; p < 2; ++p) {
    if (p) __syncthreads();
    if (wr == p) {
#pragma unroll
      for (int mi2 = 0; mi2 < 2; ++mi2) {
#pragma unroll
        for (int ni = 0; ni < 5; ++ni) {
          int col = wc * 80 + ni * 16 + lr;
          float bv = b3c[col];
#pragma unroll
          for (int j = 0; j < 4; ++j)
            plds[(mi2 * 16 + hi * 4 + j) * PSTR + col] = acc3[mi2][ni][j] + bv;
        }
      }
    }
    __syncthreads();
    {
      int rl = tid >> 5, j = tid & 31;     // rl 0..31, j 0..31
      const float* p_ = plds + rl * PSTR;
      int grow = m0 + p * 32 + rl;

      float lg[8];
#pragma unroll
      for (int k = 0; k < 8; ++k) lg[k] = p_[64 + k];
      float mx = lg[0];
#pragma unroll
      for (int k = 1; k < 8; ++k) mx = fmaxf(mx, lg[k]);
      float wgt[8], wsum = 0.0f;
#pragma unroll
      for (int k = 0; k < 8; ++k) { wgt[k] = __expf(lg[k] - mx); wsum += wgt[k]; }

      float xd = x[(size_t)grow * 64 + 32 + j];
      float zs = 0.0f, ps = 0.0f;
#pragma unroll
      for (int k = 0; k < 8; ++k) {
        float mu   = p_[96 + k * 32 + j];
        float lstd = p_[352 + k * 32 + j];
        float istd = __expf(-lstd);
        float u = (xd - mu) * istd;
        float x2 = 0.5f * u * u;
        float e  = __expf(-x2);
        ps += wgt[k] * e * istd;
        // 0.5*erfc(|u|/sqrt2), NR rational approx (rel err < 1.2e-7), shares x2:
        float ax = fabsf(u) * 0.70710678118654752f;
        float t_ = fastrcp(fmaf(0.5f, ax, 1.0f));
        float poly = -1.26551223f + t_*(1.00002368f + t_*(0.37409196f +
                     t_*(0.09678418f + t_*(-0.18628806f + t_*(0.27886807f +
                     t_*(-1.13520398f + t_*(1.48851587f + t_*(-0.82215223f +
                     t_*0.17087277f))))))));
        float erfc_half = 0.5f * t_ * __expf(poly - x2);
        float cdf = (u >= 0.0f) ? 1.0f - erfc_half : erfc_half;
        zs += wgt[k] * cdf;
      }
      float winv = fastrcp(wsum);
      float z  = zs * winv;
      float pm = ps * winv * 0.39894228040143268f;
      float logz = __logf(z), log1mz = __logf(1.0f - z);
      float ls = p_[j], bv = p_[32 + j];
      float outv = (logz - log1mz) * __expf(ls) + bv;
      float ld = __logf(pm) - logz - log1mz + ls;

      size_t base = (size_t)grow * 64;
      xo[base + j]       = x[base + j];
      xo[base + 32 + j]  = outv;
      ldo[base + j]      = 0.0f;
      ldo[base + 32 + j] = ld;
    }
  }
}

extern "C" void kernel_launch(void* const* d_in, const int* in_sizes, int n_in,
                              void* d_out, int out_size, void* d_ws, size_t ws_size,
                              hipStream_t stream) {
  const float* x  = (const float*)d_in[0];
  const float* W1 = (const float*)d_in[1];
  const float* b1 = (const float*)d_in[2];
  const float* W2 = (const float*)d_in[3];
  const float* b2 = (const float*)d_in[4];
  const float* W3 = (const float*)d_in[5];
  const float* b3 = (const float*)d_in[6];
  char* ws = (char*)d_ws;

  // Workspace: only transposed weights (~1.2 MB)
  short* w1t = (short*)ws;                  // 32 KB  bf16 [512][32]
  short* w2t = (short*)(ws + 32768);        // 512 KB bf16 [512][512]
  short* w3t = (short*)(ws + 557056);       // 640 KB bf16 [640][512]
  float* b3c = (float*)(ws + 1212416);      // 2.5 KB fp32 [640]
  float* out = (float*)d_out;

  {
    int total = 512 * 32 + 512 * 512 + NCOMPACT * 512 + NCOMPACT;
    prep_w_kernel<<<(total + 255) / 256, 256, 0, stream>>>(W1, W2, W3, b3, w1t, w2t, w3t, b3c);
  }
  mega_kernel<<<NROWS / 64, 1024, 0, stream>>>(x, w1t, b1, w2t, b2, w3t, b3c, out);
}